// Round 10
// baseline (1259.525 us; speedup 1.0000x reference)
//
#include <hip/hip_runtime.h>
#include <stdint.h>

typedef __bf16 bf16_t;
typedef bf16_t bf16x2 __attribute__((ext_vector_type(2)));
typedef bf16_t bf16x8 __attribute__((ext_vector_type(8)));
typedef float f32x4 __attribute__((ext_vector_type(4)));
typedef float f32x16 __attribute__((ext_vector_type(16)));
typedef unsigned short u16;
typedef u16 u16x8 __attribute__((ext_vector_type(8)));
typedef u16 u16x4 __attribute__((ext_vector_type(4)));
typedef unsigned int u32;
typedef u32 u32x4v __attribute__((ext_vector_type(4)));

// f32 -> bf16 RTNE (inputs finite; NaN path not needed)
__device__ __forceinline__ u16 f2b(float f) {
  uint32_t u = __builtin_bit_cast(uint32_t, f);
  u += 0x7fffu + ((u >> 16) & 1u);
  return (u16)(u >> 16);
}

__device__ __forceinline__ float b2f(u16 v) {
  u32 u = ((u32)v) << 16;
  return __builtin_bit_cast(float, u);
}

// pack two f32 -> one u32 of 2 bf16 via compiler casts (no inline asm)
__device__ __forceinline__ u32 pkbf(float lo, float hi) {
  bf16x2 t = {(__bf16)lo, (__bf16)hi};
  return __builtin_bit_cast(u32, t);
}

__device__ __forceinline__ void gl_lds16(const void* g, void* l) {
  __builtin_amdgcn_global_load_lds(
      (const __attribute__((address_space(1))) uint32_t*)(uintptr_t)g,
      (__attribute__((address_space(3))) uint32_t*)(uintptr_t)l, 16, 0, 0);
}

// ---------------- cast f32 -> bf16, 8 elems/thread ----------------
__global__ void cast_bf16(const float* __restrict__ src, u16* __restrict__ dst, int n8) {
  int i = blockIdx.x * blockDim.x + threadIdx.x;
  int stride = gridDim.x * blockDim.x;
  for (; i < n8; i += stride) {
    float4 a = ((const float4*)src)[2 * i];
    float4 b = ((const float4*)src)[2 * i + 1];
    u16x8 o;
    o[0] = f2b(a.x); o[1] = f2b(a.y); o[2] = f2b(a.z); o[3] = f2b(a.w);
    o[4] = f2b(b.x); o[5] = f2b(b.y); o[6] = f2b(b.z); o[7] = f2b(b.w);
    ((u16x8*)dst)[i] = o;
  }
}

// 4 weight matrices in one launch (blockIdx.y selects)
__global__ void cast4_bf16(const float* __restrict__ a, const float* __restrict__ b,
                           const float* __restrict__ c, const float* __restrict__ d,
                           u16* __restrict__ dst, int n8) {
  const float* srcs[4] = {a, b, c, d};
  const float* src = srcs[blockIdx.y];
  u16* dp = dst + (size_t)blockIdx.y * (size_t)n8 * 8;
  int i = blockIdx.x * blockDim.x + threadIdx.x;
  int stride = gridDim.x * blockDim.x;
  for (; i < n8; i += stride) {
    float4 x = ((const float4*)src)[2 * i];
    float4 y = ((const float4*)src)[2 * i + 1];
    u16x8 o;
    o[0] = f2b(x.x); o[1] = f2b(x.y); o[2] = f2b(x.z); o[3] = f2b(x.w);
    o[4] = f2b(y.x); o[5] = f2b(y.y); o[6] = f2b(y.z); o[7] = f2b(y.w);
    ((u16x8*)dp)[i] = o;
  }
}

// ---------------- GEMM: y = A(bf16)[8192x1024] @ W(bf16)[1024x1024]^T ----------------
// MODE 0: store bf16 row-major (scaled)       (q, k)
// MODE 1: store bf16 transposed v^T [B*H*64][2048]
// MODE 2: store f32 row-major + bias          (out proj)
template <int MODE>
__global__ __launch_bounds__(256, 2)
void gemm_bt(const u16* __restrict__ A, const u16* __restrict__ Wt,
             u16* __restrict__ outb, float* __restrict__ outf,
             const float* __restrict__ bias, float scale) {
  __shared__ u16 As[128 * 32];
  __shared__ u16 Bs[128 * 32];
  const int tid  = threadIdx.x;
  const int lane = tid & 63;
  const int w    = tid >> 6;
  const int wm   = w >> 1, wn = w & 1;
  const int g    = lane >> 4, c = lane & 15;
  const int m0   = blockIdx.y * 128, n0 = blockIdx.x * 128;

  f32x4 acc[4][4] = {};

  const u16* gA = A  + (size_t)(m0 + w * 16 + (lane >> 2)) * 1024 + (lane & 3) * 8;
  const u16* gB = Wt + (size_t)(n0 + w * 16 + (lane >> 2)) * 1024 + (lane & 3) * 8;
  char* lA = (char*)As + w * 1024;
  char* lB = (char*)Bs + w * 1024;

#pragma unroll 1
  for (int kt = 0; kt < 1024; kt += 32) {
    __syncthreads();
    gl_lds16(gA + kt,             lA);
    gl_lds16(gA + kt + 64 * 1024, lA + 4096);
    gl_lds16(gB + kt,             lB);
    gl_lds16(gB + kt + 64 * 1024, lB + 4096);
    __syncthreads();
    bf16x8 af[4], bfr[4];
#pragma unroll
    for (int mi = 0; mi < 4; ++mi)
      af[mi] = *(const bf16x8*)&As[(wm * 64 + mi * 16 + c) * 32 + g * 8];
#pragma unroll
    for (int ni = 0; ni < 4; ++ni)
      bfr[ni] = *(const bf16x8*)&Bs[(wn * 64 + ni * 16 + c) * 32 + g * 8];
#pragma unroll
    for (int mi = 0; mi < 4; ++mi)
#pragma unroll
      for (int ni = 0; ni < 4; ++ni)
        acc[mi][ni] = __builtin_amdgcn_mfma_f32_16x16x32_bf16(af[mi], bfr[ni], acc[mi][ni], 0, 0, 0);
  }

  const int rowb = m0 + wm * 64;
  const int colb = n0 + wn * 64;

  if (MODE == 0) {
#pragma unroll
    for (int mi = 0; mi < 4; ++mi)
#pragma unroll
      for (int ni = 0; ni < 4; ++ni) {
        size_t base = (size_t)(rowb + mi * 16 + g * 4) * 1024 + (colb + ni * 16 + c);
#pragma unroll
        for (int r = 0; r < 4; ++r)
          outb[base + (size_t)r * 1024] = f2b(acc[mi][ni][r] * scale);
      }
  } else if (MODE == 1) {
#pragma unroll
    for (int mi = 0; mi < 4; ++mi) {
      int row = rowb + mi * 16 + g * 4;
      int bb = row >> 11, tl = row & 2047;
#pragma unroll
      for (int ni = 0; ni < 4; ++ni) {
        int col = colb + ni * 16 + c;
        u16x4 pk;
#pragma unroll
        for (int r = 0; r < 4; ++r) pk[r] = f2b(acc[mi][ni][r]);
        *(u16x4*)(outb + ((size_t)(bb * 1024 + col)) * 2048 + tl) = pk;
      }
    }
  } else {
#pragma unroll
    for (int ni = 0; ni < 4; ++ni) {
      int col = colb + ni * 16 + c;
      float bv = bias[col];
#pragma unroll
      for (int mi = 0; mi < 4; ++mi) {
        size_t base = (size_t)(rowb + mi * 16 + g * 4) * 1024 + col;
#pragma unroll
        for (int r = 0; r < 4; ++r)
          outf[base + (size_t)r * 1024] = acc[mi][ni][r] + bv;
      }
    }
  }
}

// ---------------- fused attention v10: v5 wave shape, BLOCK-level split-K ----------
// Grid (bh=64, qt=8, kv=2). Each block = v5 exactly (4 waves x 64 q-rows, q2 ILP,
// 116 VGPR) over 1024 keys (16 steps). 1024 blocks -> 4 blocks/CU = 4 waves/SIMD
// (the v5 kernel already fits the 128-VGPR cliff; it just needed more blocks).
// Partials: unnormalized bf16 O into `part` (d_out-as-scratch, slice per kv) +
// per-row sum lp into lpb. Exact merge downstream: O=(O0+O1)/(l0+l1) (no max-sub).
// qscale folds log2(e); exp2f -> v_exp_f32 directly (no per-element mul).
__global__ __launch_bounds__(256, 4)
void attn_fused(const u16* __restrict__ qb, const u16* __restrict__ kb,
                const u16* __restrict__ vt, u16* __restrict__ part,
                float* __restrict__ lpb) {
  __shared__ u16 KV[2][4096];  // [0]=K (row=k, col=d), [1]=V^T (row=d, col=k); swizzled

  const int bh = blockIdx.x;            // 0..63
  const int qt = blockIdx.y;            // 0..7
  const int kvs = blockIdx.z;           // 0..1 : key-half
  const int b  = bh >> 4, h = bh & 15;
  const int tid  = threadIdx.x;
  const int lane = tid & 63;
  const int w    = tid >> 6;
  const int l31  = lane & 31, g32 = lane >> 5;

  // ---- staging: thread t -> rows (t>>3, t>>3+32), 16B slot (t&7), XOR-swizzled ----
  const int r  = tid >> 3, sl = tid & 7;
  const u16* kgp = kb + (size_t)(b * 2048 + kvs * 1024 + r) * 1024 + h * 64 + sl * 8;
  const u16* vgp = vt + (size_t)(bh * 64 + r) * 2048 + kvs * 1024 + sl * 8;
  const int wb = r * 128 + ((sl * 16) ^ ((r & 7) << 4));   // swizzled write byte addr
  char* lK = (char*)&KV[0][0];
  char* lV = (char*)&KV[1][0];

  // ---- Q fragments: B-operand, lane holds Q[q=l31][d=dc*16+g32*8+j]; 64 rows/wave ----
  const int qrow0 = b * 2048 + qt * 256 + w * 64;
  bf16x8 qf[2][4];
#pragma unroll
  for (int q2 = 0; q2 < 2; ++q2)
#pragma unroll
    for (int dc = 0; dc < 4; ++dc)
      qf[q2][dc] = *(const bf16x8*)(qb + (size_t)(qrow0 + q2 * 32 + l31) * 1024 +
                                    h * 64 + dc * 16 + g32 * 8);

  f32x16 Oa[2][2] = {};   // [q2][db] : O^T accumulators (this key-half)
  float lp[2] = {0.f, 0.f};

  const int xorv = (l31 & 7) << 4;      // read-side swizzle (row&7)<<4
  const int rowb = l31 * 128;           // row byte offset within 32-row half

  // prefetch step 0 into registers
  uint4 pK0 = *(const uint4*)(kgp);
  uint4 pK1 = *(const uint4*)(kgp + (size_t)32 * 1024);
  uint4 pV0 = *(const uint4*)(vgp);
  uint4 pV1 = *(const uint4*)(vgp + (size_t)32 * 2048);

#pragma unroll 1
  for (int step = 0; step < 16; ++step) {
    __syncthreads();                 // all waves done READING prev tile (WAR)
    *(uint4*)(lK + wb)        = pK0;
    *(uint4*)(lK + wb + 4096) = pK1;
    *(uint4*)(lV + wb)        = pV0;
    *(uint4*)(lV + wb + 4096) = pV1;
    if (step + 1 < 16) {             // issue next-step loads; consumed next iter
      const int s1 = (step + 1) * 64;
      pK0 = *(const uint4*)(kgp + (size_t)s1 * 1024);
      pK1 = *(const uint4*)(kgp + (size_t)(s1 + 32) * 1024);
      pV0 = *(const uint4*)(vgp + s1);
      pV1 = *(const uint4*)(vgp + s1 + (size_t)32 * 2048);
    }
    __syncthreads();                 // ds_writes visible to all waves

    const char* kt  = (const char*)&KV[0][0];
    const char* vtl = (const char*)&KV[1][0];

#pragma unroll
    for (int kb2 = 0; kb2 < 2; ++kb2) {
      // K fragments: A-operand, lane holds K[k=kb2*32+l31][d=dc*16+g32*8+j]
      bf16x8 kf[4];
#pragma unroll
      for (int dc = 0; dc < 4; ++dc)
        kf[dc] = *(const bf16x8*)(kt + kb2 * 4096 + rowb + ((dc * 32 + g32 * 16) ^ xorv));
      // V fragments: A-operand, lane holds V^T[d=db*32+l31][k=(kb2*2+ck)*16+g32*8+j]
      bf16x8 vf[2][2];
#pragma unroll
      for (int db = 0; db < 2; ++db)
#pragma unroll
        for (int ck = 0; ck < 2; ++ck)
          vf[db][ck] = *(const bf16x8*)(vtl + db * 4096 + rowb +
                                        (((kb2 * 2 + ck) * 32 + g32 * 16) ^ xorv));

#pragma unroll
      for (int q2 = 0; q2 < 2; ++q2) {
        f32x16 S = {};
#pragma unroll
        for (int dc = 0; dc < 4; ++dc)
          S = __builtin_amdgcn_mfma_f32_32x32x16_bf16(kf[dc], qf[q2][dc], S, 0, 0, 0);

        // in-register softmax (no max-sub; S pre-scaled by log2e -> exp2)
        float p[16];
#pragma unroll
        for (int rr = 0; rr < 16; ++rr) p[rr] = exp2f(S[rr]);
        float s01 = (p[0] + p[1]) + (p[2] + p[3]);
        float s02 = (p[4] + p[5]) + (p[6] + p[7]);
        float s03 = (p[8] + p[9]) + (p[10] + p[11]);
        float s04 = (p[12] + p[13]) + (p[14] + p[15]);
        lp[q2] += (s01 + s02) + (s03 + s04);

        // ---- P^T -> bf16 B-operand words (shfl half-exchange) ----
        u32 w0 = pkbf(p[0], p[1]),   w1 = pkbf(p[2], p[3]);
        u32 w2 = pkbf(p[4], p[5]),   w3 = pkbf(p[6], p[7]);
        u32 w4 = pkbf(p[8], p[9]),   w5 = pkbf(p[10], p[11]);
        u32 w6 = pkbf(p[12], p[13]), w7 = pkbf(p[14], p[15]);
        u32 e0 = __shfl_xor(w0, 32), e1 = __shfl_xor(w1, 32);
        u32 e2 = __shfl_xor(w2, 32), e3 = __shfl_xor(w3, 32);
        u32 e4 = __shfl_xor(w4, 32), e5 = __shfl_xor(w5, 32);
        u32 e6 = __shfl_xor(w6, 32), e7 = __shfl_xor(w7, 32);
        u32x4v q0 = {g32 ? e2 : w0, g32 ? e3 : w1, g32 ? w2 : e0, g32 ? w3 : e1};
        u32x4v q1 = {g32 ? e6 : w4, g32 ? e7 : w5, g32 ? w6 : e4, g32 ? w7 : e5};
        bf16x8 pb0 = __builtin_bit_cast(bf16x8, q0);
        bf16x8 pb1 = __builtin_bit_cast(bf16x8, q1);

#pragma unroll
        for (int db = 0; db < 2; ++db) {
          Oa[q2][db] = __builtin_amdgcn_mfma_f32_32x32x16_bf16(vf[db][0], pb0, Oa[q2][db], 0, 0, 0);
          Oa[q2][db] = __builtin_amdgcn_mfma_f32_32x32x16_bf16(vf[db][1], pb1, Oa[q2][db], 0, 0, 0);
        }
      }
    }
  }

  // ---- epilogue: store UNNORMALIZED bf16 partial O + per-row lp ----
  u16* pb = part + (size_t)kvs * 8388608;
#pragma unroll
  for (int q2 = 0; q2 < 2; ++q2) {
    float v = lp[q2];
    v += __shfl_xor(v, 32);
    const int trow = qt * 256 + w * 64 + q2 * 32 + l31;
    if (g32 == 0) lpb[(size_t)kvs * 131072 + bh * 2048 + trow] = v;
    const size_t rb = (size_t)(b * 2048 + trow) * 1024 + h * 64;
#pragma unroll
    for (int db = 0; db < 2; ++db)
#pragma unroll
      for (int pr = 0; pr < 8; ++pr) {
        int reg = 2 * pr;
        int d0  = (reg & 3) + 8 * (reg >> 2) + 4 * g32 + db * 32;
        u32 pk = pkbf(Oa[q2][db][reg], Oa[q2][db][reg + 1]);
        *(u32*)(pb + rb + d0) = pk;
      }
  }
}

// ---------------- combine: out = (P0 + P1) / (l0 + l1), bf16, 8 elems/thread ------
__global__ __launch_bounds__(256)
void combine_halves(const u16* __restrict__ part, const float* __restrict__ lpb,
                    u16* __restrict__ ob) {
  int i = blockIdx.x * blockDim.x + threadIdx.x;   // 0..1M-1, 8 elems each
  const int e = i * 8;
  const int h = (e >> 6) & 15;
  const int t = (e >> 10) & 2047;
  const int b = e >> 21;
  const int row = ((b * 16 + h) << 11) + t;
  float rinv = 1.0f / (lpb[row] + lpb[131072 + row]);
  u16x8 p0 = *(const u16x8*)(part + e);
  u16x8 p1 = *(const u16x8*)(part + 8388608 + e);
  u16x8 o;
#pragma unroll
  for (int j = 0; j < 8; ++j)
    o[j] = f2b((b2f(p0[j]) + b2f(p1[j])) * rinv);
  *(u16x8*)(ob + e) = o;
}

// ---------------- host ----------------
extern "C" void kernel_launch(void* const* d_in, const int* in_sizes, int n_in,
                              void* d_out, int out_size, void* d_ws, size_t ws_size,
                              hipStream_t stream) {
  const float* x  = (const float*)d_in[0];
  const float* Wk = (const float*)d_in[1];
  const float* Wq = (const float*)d_in[2];
  const float* Wv = (const float*)d_in[3];
  const float* Wp = (const float*)d_in[4];
  const float* bp = (const float*)d_in[5];
  float* out = (float*)d_out;

  const size_t MC = (size_t)8192 * 1024;
  u16* xb  = (u16*)d_ws;
  u16* qb  = xb + MC;
  u16* kb2 = qb + MC;
  u16* vtb = kb2 + MC;
  u16* wqb = vtb + MC;   // 4 weight buffers contiguous: wq, wk, wv, wp
  u16* wkb = wqb + (size_t)1024 * 1024;
  u16* wvb = wkb + (size_t)1024 * 1024;
  u16* wpb = wvb + (size_t)1024 * 1024;
  u16* ob  = xb;                // xb dead after V GEMM; reuse for attention output
  u16* part = (u16*)d_out;      // d_out as scratch: 2 slices x 8M bf16 = 32MB (exact)
  float* lpb = (float*)wqb;     // wq weights dead after q GEMM; 2x128K floats = 1MB

  cast_bf16<<<2048, 256, 0, stream>>>(x, xb, (int)(MC / 8));
  cast4_bf16<<<dim3(256, 4), 256, 0, stream>>>(Wq, Wk, Wv, Wp, wqb, 1024 * 1024 / 8);

  const float qscale = 0.125f * 1.44269504088896340736f;  // 1/sqrt(D) * log2(e)
  dim3 gg(8, 64);  // (N/128, M/128)
  gemm_bt<0><<<gg, 256, 0, stream>>>(xb, wqb, qb,  nullptr, nullptr, qscale);  // q
  gemm_bt<0><<<gg, 256, 0, stream>>>(xb, wkb, kb2, nullptr, nullptr, 1.0f);    // k
  gemm_bt<1><<<gg, 256, 0, stream>>>(xb, wvb, vtb, nullptr, nullptr, 1.0f);    // v^T

  attn_fused<<<dim3(64, 8, 2), 256, 0, stream>>>(qb, kb2, vtb, part, lpb);
  combine_halves<<<4096, 256, 0, stream>>>(part, lpb, ob);

  gemm_bt<2><<<gg, 256, 0, stream>>>(ob, wpb, nullptr, out, bp, 1.0f);         // out proj + bias
}

// Round 11
// 247.999 us; speedup vs baseline: 5.0788x; 5.0788x over previous
//
#include <hip/hip_runtime.h>
#include <stdint.h>

typedef __bf16 bf16_t;
typedef bf16_t bf16x2 __attribute__((ext_vector_type(2)));
typedef bf16_t bf16x8 __attribute__((ext_vector_type(8)));
typedef float f32x4 __attribute__((ext_vector_type(4)));
typedef float f32x16 __attribute__((ext_vector_type(16)));
typedef unsigned short u16;
typedef u16 u16x8 __attribute__((ext_vector_type(8)));
typedef u16 u16x4 __attribute__((ext_vector_type(4)));
typedef unsigned int u32;
typedef u32 u32x4v __attribute__((ext_vector_type(4)));

// f32 -> bf16 RTNE (inputs finite; NaN path not needed)
__device__ __forceinline__ u16 f2b(float f) {
  uint32_t u = __builtin_bit_cast(uint32_t, f);
  u += 0x7fffu + ((u >> 16) & 1u);
  return (u16)(u >> 16);
}

__device__ __forceinline__ float b2f(u16 v) {
  u32 u = ((u32)v) << 16;
  return __builtin_bit_cast(float, u);
}

// pack two f32 -> one u32 of 2 bf16 via compiler casts (no inline asm)
__device__ __forceinline__ u32 pkbf(float lo, float hi) {
  bf16x2 t = {(__bf16)lo, (__bf16)hi};
  return __builtin_bit_cast(u32, t);
}

__device__ __forceinline__ void gl_lds16(const void* g, void* l) {
  __builtin_amdgcn_global_load_lds(
      (const __attribute__((address_space(1))) uint32_t*)(uintptr_t)g,
      (__attribute__((address_space(3))) uint32_t*)(uintptr_t)l, 16, 0, 0);
}

// ---------------- cast f32 -> bf16, 8 elems/thread ----------------
__global__ void cast_bf16(const float* __restrict__ src, u16* __restrict__ dst, int n8) {
  int i = blockIdx.x * blockDim.x + threadIdx.x;
  int stride = gridDim.x * blockDim.x;
  for (; i < n8; i += stride) {
    float4 a = ((const float4*)src)[2 * i];
    float4 b = ((const float4*)src)[2 * i + 1];
    u16x8 o;
    o[0] = f2b(a.x); o[1] = f2b(a.y); o[2] = f2b(a.z); o[3] = f2b(a.w);
    o[4] = f2b(b.x); o[5] = f2b(b.y); o[6] = f2b(b.z); o[7] = f2b(b.w);
    ((u16x8*)dst)[i] = o;
  }
}

// 4 weight matrices in one launch (blockIdx.y selects)
__global__ void cast4_bf16(const float* __restrict__ a, const float* __restrict__ b,
                           const float* __restrict__ c, const float* __restrict__ d,
                           u16* __restrict__ dst, int n8) {
  const float* srcs[4] = {a, b, c, d};
  const float* src = srcs[blockIdx.y];
  u16* dp = dst + (size_t)blockIdx.y * (size_t)n8 * 8;
  int i = blockIdx.x * blockDim.x + threadIdx.x;
  int stride = gridDim.x * blockDim.x;
  for (; i < n8; i += stride) {
    float4 x = ((const float4*)src)[2 * i];
    float4 y = ((const float4*)src)[2 * i + 1];
    u16x8 o;
    o[0] = f2b(x.x); o[1] = f2b(x.y); o[2] = f2b(x.z); o[3] = f2b(x.w);
    o[4] = f2b(y.x); o[5] = f2b(y.y); o[6] = f2b(y.z); o[7] = f2b(y.w);
    ((u16x8*)dp)[i] = o;
  }
}

// ---------------- GEMM: y = A(bf16)[8192x1024] @ W(bf16)[1024x1024]^T ----------------
// MODE 0: store bf16 row-major (scaled)       (q, k)
// MODE 1: store bf16 transposed v^T [B*H*64][2048]
// MODE 2: store f32 row-major + bias          (out proj)
template <int MODE>
__global__ __launch_bounds__(256, 2)
void gemm_bt(const u16* __restrict__ A, const u16* __restrict__ Wt,
             u16* __restrict__ outb, float* __restrict__ outf,
             const float* __restrict__ bias, float scale) {
  __shared__ u16 As[128 * 32];
  __shared__ u16 Bs[128 * 32];
  const int tid  = threadIdx.x;
  const int lane = tid & 63;
  const int w    = tid >> 6;
  const int wm   = w >> 1, wn = w & 1;
  const int g    = lane >> 4, c = lane & 15;
  const int m0   = blockIdx.y * 128, n0 = blockIdx.x * 128;

  f32x4 acc[4][4] = {};

  const u16* gA = A  + (size_t)(m0 + w * 16 + (lane >> 2)) * 1024 + (lane & 3) * 8;
  const u16* gB = Wt + (size_t)(n0 + w * 16 + (lane >> 2)) * 1024 + (lane & 3) * 8;
  char* lA = (char*)As + w * 1024;
  char* lB = (char*)Bs + w * 1024;

#pragma unroll 1
  for (int kt = 0; kt < 1024; kt += 32) {
    __syncthreads();
    gl_lds16(gA + kt,             lA);
    gl_lds16(gA + kt + 64 * 1024, lA + 4096);
    gl_lds16(gB + kt,             lB);
    gl_lds16(gB + kt + 64 * 1024, lB + 4096);
    __syncthreads();
    bf16x8 af[4], bfr[4];
#pragma unroll
    for (int mi = 0; mi < 4; ++mi)
      af[mi] = *(const bf16x8*)&As[(wm * 64 + mi * 16 + c) * 32 + g * 8];
#pragma unroll
    for (int ni = 0; ni < 4; ++ni)
      bfr[ni] = *(const bf16x8*)&Bs[(wn * 64 + ni * 16 + c) * 32 + g * 8];
#pragma unroll
    for (int mi = 0; mi < 4; ++mi)
#pragma unroll
      for (int ni = 0; ni < 4; ++ni)
        acc[mi][ni] = __builtin_amdgcn_mfma_f32_16x16x32_bf16(af[mi], bfr[ni], acc[mi][ni], 0, 0, 0);
  }

  const int rowb = m0 + wm * 64;
  const int colb = n0 + wn * 64;

  if (MODE == 0) {
#pragma unroll
    for (int mi = 0; mi < 4; ++mi)
#pragma unroll
      for (int ni = 0; ni < 4; ++ni) {
        size_t base = (size_t)(rowb + mi * 16 + g * 4) * 1024 + (colb + ni * 16 + c);
#pragma unroll
        for (int r = 0; r < 4; ++r)
          outb[base + (size_t)r * 1024] = f2b(acc[mi][ni][r] * scale);
      }
  } else if (MODE == 1) {
#pragma unroll
    for (int mi = 0; mi < 4; ++mi) {
      int row = rowb + mi * 16 + g * 4;
      int bb = row >> 11, tl = row & 2047;
#pragma unroll
      for (int ni = 0; ni < 4; ++ni) {
        int col = colb + ni * 16 + c;
        u16x4 pk;
#pragma unroll
        for (int r = 0; r < 4; ++r) pk[r] = f2b(acc[mi][ni][r]);
        *(u16x4*)(outb + ((size_t)(bb * 1024 + col)) * 2048 + tl) = pk;
      }
    }
  } else {
#pragma unroll
    for (int ni = 0; ni < 4; ++ni) {
      int col = colb + ni * 16 + c;
      float bv = bias[col];
#pragma unroll
      for (int mi = 0; mi < 4; ++mi) {
        size_t base = (size_t)(rowb + mi * 16 + g * 4) * 1024 + col;
#pragma unroll
        for (int r = 0; r < 4; ++r)
          outf[base + (size_t)r * 1024] = acc[mi][ni][r] + bv;
      }
    }
  }
}

// ---------------- fused attention v11: v10 with launch_bounds reverted to (256,2) --
// v10's (256,4) forced a 128-VGPR allocator target it couldn't meet -> spill (64
// VGPR, GBs of scratch). (256,2) compiles this body at ~116 VGPR (v5-measured);
// the HW then runs 4 waves/SIMD at runtime anyway (floor(512/116)=4), and the
// 1024-block grid (kv split z=2) supplies the blocks v5 lacked. Split-K merge
// correctness was verified by R10's pass (absmax 4.88e-4).
__global__ __launch_bounds__(256, 2)
void attn_fused(const u16* __restrict__ qb, const u16* __restrict__ kb,
                const u16* __restrict__ vt, u16* __restrict__ part,
                float* __restrict__ lpb) {
  __shared__ u16 KV[2][4096];  // [0]=K (row=k, col=d), [1]=V^T (row=d, col=k); swizzled

  const int bh = blockIdx.x;            // 0..63
  const int qt = blockIdx.y;            // 0..7
  const int kvs = blockIdx.z;           // 0..1 : key-half
  const int b  = bh >> 4, h = bh & 15;
  const int tid  = threadIdx.x;
  const int lane = tid & 63;
  const int w    = tid >> 6;
  const int l31  = lane & 31, g32 = lane >> 5;

  // ---- staging: thread t -> rows (t>>3, t>>3+32), 16B slot (t&7), XOR-swizzled ----
  const int r  = tid >> 3, sl = tid & 7;
  const u16* kgp = kb + (size_t)(b * 2048 + kvs * 1024 + r) * 1024 + h * 64 + sl * 8;
  const u16* vgp = vt + (size_t)(bh * 64 + r) * 2048 + kvs * 1024 + sl * 8;
  const int wb = r * 128 + ((sl * 16) ^ ((r & 7) << 4));   // swizzled write byte addr
  char* lK = (char*)&KV[0][0];
  char* lV = (char*)&KV[1][0];

  // ---- Q fragments: B-operand, lane holds Q[q=l31][d=dc*16+g32*8+j]; 64 rows/wave ----
  const int qrow0 = b * 2048 + qt * 256 + w * 64;
  bf16x8 qf[2][4];
#pragma unroll
  for (int q2 = 0; q2 < 2; ++q2)
#pragma unroll
    for (int dc = 0; dc < 4; ++dc)
      qf[q2][dc] = *(const bf16x8*)(qb + (size_t)(qrow0 + q2 * 32 + l31) * 1024 +
                                    h * 64 + dc * 16 + g32 * 8);

  f32x16 Oa[2][2] = {};   // [q2][db] : O^T accumulators (this key-half)
  float lp[2] = {0.f, 0.f};

  const int xorv = (l31 & 7) << 4;      // read-side swizzle (row&7)<<4
  const int rowb = l31 * 128;           // row byte offset within 32-row half

  // prefetch step 0 into registers
  uint4 pK0 = *(const uint4*)(kgp);
  uint4 pK1 = *(const uint4*)(kgp + (size_t)32 * 1024);
  uint4 pV0 = *(const uint4*)(vgp);
  uint4 pV1 = *(const uint4*)(vgp + (size_t)32 * 2048);

#pragma unroll 1
  for (int step = 0; step < 16; ++step) {
    __syncthreads();                 // all waves done READING prev tile (WAR)
    *(uint4*)(lK + wb)        = pK0;
    *(uint4*)(lK + wb + 4096) = pK1;
    *(uint4*)(lV + wb)        = pV0;
    *(uint4*)(lV + wb + 4096) = pV1;
    if (step + 1 < 16) {             // issue next-step loads; consumed next iter
      const int s1 = (step + 1) * 64;
      pK0 = *(const uint4*)(kgp + (size_t)s1 * 1024);
      pK1 = *(const uint4*)(kgp + (size_t)(s1 + 32) * 1024);
      pV0 = *(const uint4*)(vgp + s1);
      pV1 = *(const uint4*)(vgp + s1 + (size_t)32 * 2048);
    }
    __syncthreads();                 // ds_writes visible to all waves

    const char* kt  = (const char*)&KV[0][0];
    const char* vtl = (const char*)&KV[1][0];

#pragma unroll
    for (int kb2 = 0; kb2 < 2; ++kb2) {
      // K fragments: A-operand, lane holds K[k=kb2*32+l31][d=dc*16+g32*8+j]
      bf16x8 kf[4];
#pragma unroll
      for (int dc = 0; dc < 4; ++dc)
        kf[dc] = *(const bf16x8*)(kt + kb2 * 4096 + rowb + ((dc * 32 + g32 * 16) ^ xorv));
      // V fragments: A-operand, lane holds V^T[d=db*32+l31][k=(kb2*2+ck)*16+g32*8+j]
      bf16x8 vf[2][2];
#pragma unroll
      for (int db = 0; db < 2; ++db)
#pragma unroll
        for (int ck = 0; ck < 2; ++ck)
          vf[db][ck] = *(const bf16x8*)(vtl + db * 4096 + rowb +
                                        (((kb2 * 2 + ck) * 32 + g32 * 16) ^ xorv));

#pragma unroll
      for (int q2 = 0; q2 < 2; ++q2) {
        f32x16 S = {};
#pragma unroll
        for (int dc = 0; dc < 4; ++dc)
          S = __builtin_amdgcn_mfma_f32_32x32x16_bf16(kf[dc], qf[q2][dc], S, 0, 0, 0);

        // in-register softmax (no max-sub; S pre-scaled by log2e -> exp2)
        float p[16];
#pragma unroll
        for (int rr = 0; rr < 16; ++rr) p[rr] = exp2f(S[rr]);
        float s01 = (p[0] + p[1]) + (p[2] + p[3]);
        float s02 = (p[4] + p[5]) + (p[6] + p[7]);
        float s03 = (p[8] + p[9]) + (p[10] + p[11]);
        float s04 = (p[12] + p[13]) + (p[14] + p[15]);
        lp[q2] += (s01 + s02) + (s03 + s04);

        // ---- P^T -> bf16 B-operand words (shfl half-exchange) ----
        u32 w0 = pkbf(p[0], p[1]),   w1 = pkbf(p[2], p[3]);
        u32 w2 = pkbf(p[4], p[5]),   w3 = pkbf(p[6], p[7]);
        u32 w4 = pkbf(p[8], p[9]),   w5 = pkbf(p[10], p[11]);
        u32 w6 = pkbf(p[12], p[13]), w7 = pkbf(p[14], p[15]);
        u32 e0 = __shfl_xor(w0, 32), e1 = __shfl_xor(w1, 32);
        u32 e2 = __shfl_xor(w2, 32), e3 = __shfl_xor(w3, 32);
        u32 e4 = __shfl_xor(w4, 32), e5 = __shfl_xor(w5, 32);
        u32 e6 = __shfl_xor(w6, 32), e7 = __shfl_xor(w7, 32);
        u32x4v q0 = {g32 ? e2 : w0, g32 ? e3 : w1, g32 ? w2 : e0, g32 ? w3 : e1};
        u32x4v q1 = {g32 ? e6 : w4, g32 ? e7 : w5, g32 ? w6 : e4, g32 ? w7 : e5};
        bf16x8 pb0 = __builtin_bit_cast(bf16x8, q0);
        bf16x8 pb1 = __builtin_bit_cast(bf16x8, q1);

#pragma unroll
        for (int db = 0; db < 2; ++db) {
          Oa[q2][db] = __builtin_amdgcn_mfma_f32_32x32x16_bf16(vf[db][0], pb0, Oa[q2][db], 0, 0, 0);
          Oa[q2][db] = __builtin_amdgcn_mfma_f32_32x32x16_bf16(vf[db][1], pb1, Oa[q2][db], 0, 0, 0);
        }
      }
    }
  }

  // ---- epilogue: store UNNORMALIZED bf16 partial O + per-row lp ----
  u16* pb = part + (size_t)kvs * 8388608;
#pragma unroll
  for (int q2 = 0; q2 < 2; ++q2) {
    float v = lp[q2];
    v += __shfl_xor(v, 32);
    const int trow = qt * 256 + w * 64 + q2 * 32 + l31;
    if (g32 == 0) lpb[(size_t)kvs * 131072 + bh * 2048 + trow] = v;
    const size_t rb = (size_t)(b * 2048 + trow) * 1024 + h * 64;
#pragma unroll
    for (int db = 0; db < 2; ++db)
#pragma unroll
      for (int pr = 0; pr < 8; ++pr) {
        int reg = 2 * pr;
        int d0  = (reg & 3) + 8 * (reg >> 2) + 4 * g32 + db * 32;
        u32 pk = pkbf(Oa[q2][db][reg], Oa[q2][db][reg + 1]);
        *(u32*)(pb + rb + d0) = pk;
      }
  }
}

// ---------------- combine: out = (P0 + P1) / (l0 + l1), bf16, 8 elems/thread ------
__global__ __launch_bounds__(256)
void combine_halves(const u16* __restrict__ part, const float* __restrict__ lpb,
                    u16* __restrict__ ob) {
  int i = blockIdx.x * blockDim.x + threadIdx.x;   // 0..1M-1, 8 elems each
  const int e = i * 8;
  const int h = (e >> 6) & 15;
  const int t = (e >> 10) & 2047;
  const int b = e >> 21;
  const int row = ((b * 16 + h) << 11) + t;
  float rinv = 1.0f / (lpb[row] + lpb[131072 + row]);
  u16x8 p0 = *(const u16x8*)(part + e);
  u16x8 p1 = *(const u16x8*)(part + 8388608 + e);
  u16x8 o;
#pragma unroll
  for (int j = 0; j < 8; ++j)
    o[j] = f2b((b2f(p0[j]) + b2f(p1[j])) * rinv);
  *(u16x8*)(ob + e) = o;
}

// ---------------- host ----------------
extern "C" void kernel_launch(void* const* d_in, const int* in_sizes, int n_in,
                              void* d_out, int out_size, void* d_ws, size_t ws_size,
                              hipStream_t stream) {
  const float* x  = (const float*)d_in[0];
  const float* Wk = (const float*)d_in[1];
  const float* Wq = (const float*)d_in[2];
  const float* Wv = (const float*)d_in[3];
  const float* Wp = (const float*)d_in[4];
  const float* bp = (const float*)d_in[5];
  float* out = (float*)d_out;

  const size_t MC = (size_t)8192 * 1024;
  u16* xb  = (u16*)d_ws;
  u16* qb  = xb + MC;
  u16* kb2 = qb + MC;
  u16* vtb = kb2 + MC;
  u16* wqb = vtb + MC;   // 4 weight buffers contiguous: wq, wk, wv, wp
  u16* wkb = wqb + (size_t)1024 * 1024;
  u16* wvb = wkb + (size_t)1024 * 1024;
  u16* wpb = wvb + (size_t)1024 * 1024;
  u16* ob  = xb;                // xb dead after V GEMM; reuse for attention output
  u16* part = (u16*)d_out;      // d_out as scratch: 2 slices x 8M bf16 = 32MB (exact)
  float* lpb = (float*)wqb;     // wq weights dead after q GEMM; 2x128K floats = 1MB

  cast_bf16<<<2048, 256, 0, stream>>>(x, xb, (int)(MC / 8));
  cast4_bf16<<<dim3(256, 4), 256, 0, stream>>>(Wq, Wk, Wv, Wp, wqb, 1024 * 1024 / 8);

  const float qscale = 0.125f * 1.44269504088896340736f;  // 1/sqrt(D) * log2(e)
  dim3 gg(8, 64);  // (N/128, M/128)
  gemm_bt<0><<<gg, 256, 0, stream>>>(xb, wqb, qb,  nullptr, nullptr, qscale);  // q
  gemm_bt<0><<<gg, 256, 0, stream>>>(xb, wkb, kb2, nullptr, nullptr, 1.0f);    // k
  gemm_bt<1><<<gg, 256, 0, stream>>>(xb, wvb, vtb, nullptr, nullptr, 1.0f);    // v^T

  attn_fused<<<dim3(64, 8, 2), 256, 0, stream>>>(qb, kb2, vtb, part, lpb);
  combine_halves<<<4096, 256, 0, stream>>>(part, lpb, ob);

  gemm_bt<2><<<gg, 256, 0, stream>>>(ob, wpb, nullptr, out, bp, 1.0f);         // out proj + bias
}

// Round 12
// 206.855 us; speedup vs baseline: 6.0889x; 1.1989x over previous
//
#include <hip/hip_runtime.h>
#include <stdint.h>

typedef __bf16 bf16_t;
typedef bf16_t bf16x2 __attribute__((ext_vector_type(2)));
typedef bf16_t bf16x8 __attribute__((ext_vector_type(8)));
typedef float f32x4 __attribute__((ext_vector_type(4)));
typedef float f32x16 __attribute__((ext_vector_type(16)));
typedef unsigned short u16;
typedef u16 u16x8 __attribute__((ext_vector_type(8)));
typedef u16 u16x4 __attribute__((ext_vector_type(4)));
typedef unsigned int u32;
typedef u32 u32x2 __attribute__((ext_vector_type(2)));
typedef u32 u32x4v __attribute__((ext_vector_type(4)));

// f32 -> bf16 RTNE (inputs finite; NaN path not needed)
__device__ __forceinline__ u16 f2b(float f) {
  uint32_t u = __builtin_bit_cast(uint32_t, f);
  u += 0x7fffu + ((u >> 16) & 1u);
  return (u16)(u >> 16);
}

// pack two f32 -> one u32 of 2 bf16 via compiler casts (no inline asm)
__device__ __forceinline__ u32 pkbf(float lo, float hi) {
  bf16x2 t = {(__bf16)lo, (__bf16)hi};
  return __builtin_bit_cast(u32, t);
}

__device__ __forceinline__ void gl_lds16(const void* g, void* l) {
  __builtin_amdgcn_global_load_lds(
      (const __attribute__((address_space(1))) uint32_t*)(uintptr_t)g,
      (__attribute__((address_space(3))) uint32_t*)(uintptr_t)l, 16, 0, 0);
}

// ---------------- cast f32 -> bf16, 8 elems/thread ----------------
__global__ void cast_bf16(const float* __restrict__ src, u16* __restrict__ dst, int n8) {
  int i = blockIdx.x * blockDim.x + threadIdx.x;
  int stride = gridDim.x * blockDim.x;
  for (; i < n8; i += stride) {
    float4 a = ((const float4*)src)[2 * i];
    float4 b = ((const float4*)src)[2 * i + 1];
    u16x8 o;
    o[0] = f2b(a.x); o[1] = f2b(a.y); o[2] = f2b(a.z); o[3] = f2b(a.w);
    o[4] = f2b(b.x); o[5] = f2b(b.y); o[6] = f2b(b.z); o[7] = f2b(b.w);
    ((u16x8*)dst)[i] = o;
  }
}

// 4 weight matrices in one launch (blockIdx.y selects)
__global__ void cast4_bf16(const float* __restrict__ a, const float* __restrict__ b,
                           const float* __restrict__ c, const float* __restrict__ d,
                           u16* __restrict__ dst, int n8) {
  const float* srcs[4] = {a, b, c, d};
  const float* src = srcs[blockIdx.y];
  u16* dp = dst + (size_t)blockIdx.y * (size_t)n8 * 8;
  int i = blockIdx.x * blockDim.x + threadIdx.x;
  int stride = gridDim.x * blockDim.x;
  for (; i < n8; i += stride) {
    float4 x = ((const float4*)src)[2 * i];
    float4 y = ((const float4*)src)[2 * i + 1];
    u16x8 o;
    o[0] = f2b(x.x); o[1] = f2b(x.y); o[2] = f2b(x.z); o[3] = f2b(x.w);
    o[4] = f2b(y.x); o[5] = f2b(y.y); o[6] = f2b(y.z); o[7] = f2b(y.w);
    ((u16x8*)dp)[i] = o;
  }
}

// ---------------- GEMM: y = A(bf16)[8192x1024] @ W(bf16)[1024x1024]^T ----------------
// MODE 0: store bf16 row-major (scaled)       (q, k)
// MODE 1: store bf16 transposed v^T [B*H*64][2048]
// MODE 2: store f32 row-major + bias          (out proj)
template <int MODE>
__global__ __launch_bounds__(256, 2)
void gemm_bt(const u16* __restrict__ A, const u16* __restrict__ Wt,
             u16* __restrict__ outb, float* __restrict__ outf,
             const float* __restrict__ bias, float scale) {
  __shared__ u16 As[128 * 32];
  __shared__ u16 Bs[128 * 32];
  const int tid  = threadIdx.x;
  const int lane = tid & 63;
  const int w    = tid >> 6;
  const int wm   = w >> 1, wn = w & 1;
  const int g    = lane >> 4, c = lane & 15;
  const int m0   = blockIdx.y * 128, n0 = blockIdx.x * 128;

  f32x4 acc[4][4] = {};

  const u16* gA = A  + (size_t)(m0 + w * 16 + (lane >> 2)) * 1024 + (lane & 3) * 8;
  const u16* gB = Wt + (size_t)(n0 + w * 16 + (lane >> 2)) * 1024 + (lane & 3) * 8;
  char* lA = (char*)As + w * 1024;
  char* lB = (char*)Bs + w * 1024;

#pragma unroll 1
  for (int kt = 0; kt < 1024; kt += 32) {
    __syncthreads();
    gl_lds16(gA + kt,             lA);
    gl_lds16(gA + kt + 64 * 1024, lA + 4096);
    gl_lds16(gB + kt,             lB);
    gl_lds16(gB + kt + 64 * 1024, lB + 4096);
    __syncthreads();
    bf16x8 af[4], bfr[4];
#pragma unroll
    for (int mi = 0; mi < 4; ++mi)
      af[mi] = *(const bf16x8*)&As[(wm * 64 + mi * 16 + c) * 32 + g * 8];
#pragma unroll
    for (int ni = 0; ni < 4; ++ni)
      bfr[ni] = *(const bf16x8*)&Bs[(wn * 64 + ni * 16 + c) * 32 + g * 8];
#pragma unroll
    for (int mi = 0; mi < 4; ++mi)
#pragma unroll
      for (int ni = 0; ni < 4; ++ni)
        acc[mi][ni] = __builtin_amdgcn_mfma_f32_16x16x32_bf16(af[mi], bfr[ni], acc[mi][ni], 0, 0, 0);
  }

  const int rowb = m0 + wm * 64;
  const int colb = n0 + wn * 64;

  if (MODE == 0) {
#pragma unroll
    for (int mi = 0; mi < 4; ++mi)
#pragma unroll
      for (int ni = 0; ni < 4; ++ni) {
        size_t base = (size_t)(rowb + mi * 16 + g * 4) * 1024 + (colb + ni * 16 + c);
#pragma unroll
        for (int r = 0; r < 4; ++r)
          outb[base + (size_t)r * 1024] = f2b(acc[mi][ni][r] * scale);
      }
  } else if (MODE == 1) {
#pragma unroll
    for (int mi = 0; mi < 4; ++mi) {
      int row = rowb + mi * 16 + g * 4;
      int bb = row >> 11, tl = row & 2047;
#pragma unroll
      for (int ni = 0; ni < 4; ++ni) {
        int col = colb + ni * 16 + c;
        u16x4 pk;
#pragma unroll
        for (int r = 0; r < 4; ++r) pk[r] = f2b(acc[mi][ni][r]);
        *(u16x4*)(outb + ((size_t)(bb * 1024 + col)) * 2048 + tl) = pk;
      }
    }
  } else {
#pragma unroll
    for (int ni = 0; ni < 4; ++ni) {
      int col = colb + ni * 16 + c;
      float bv = bias[col];
#pragma unroll
      for (int mi = 0; mi < 4; ++mi) {
        size_t base = (size_t)(rowb + mi * 16 + g * 4) * 1024 + col;
#pragma unroll
        for (int r = 0; r < 4; ++r)
          outf[base + (size_t)r * 1024] = acc[mi][ni][r] + bv;
      }
    }
  }
}

// ---------------- fused attention v12: v9 frame + permlane32_swap + raw exp2 -------
// Back to the 95us champion (v5/v9: grid 64x8, 4 waves x 64 q-rows, 32 steps, no
// split-K). Two micro-changes, both builtins (compiler-visible, no asm hazards):
//  1) P half-exchange via __builtin_amdgcn_permlane32_swap (T12 primitive, VALU
//     full-rate) replacing 8 ds_bpermute (__shfl_xor) + 8 cndmask-selects per
//     sub-tile. swap(w0,w2) = {word0, word2} == v5's {g32?e2:w0,...} selects
//     (verified algebraically; v2's small-error run used the same pairing).
//  2) exp(S) = exp2(S * log2e) with log2e folded into the Q GEMM scale and
//     __builtin_amdgcn_exp2f (one v_exp_f32 vs __expf's v_mul+v_exp).
__global__ __launch_bounds__(256, 2)
void attn_fused(const u16* __restrict__ qb, const u16* __restrict__ kb,
                const u16* __restrict__ vt, u16* __restrict__ ob) {
  __shared__ u16 KV[2][4096];  // [0]=K (row=k, col=d), [1]=V^T (row=d, col=k); swizzled

  const int bh = blockIdx.x;            // 0..63
  const int qt = blockIdx.y;            // 0..7
  const int b  = bh >> 4, h = bh & 15;
  const int tid  = threadIdx.x;
  const int lane = tid & 63;
  const int w    = tid >> 6;
  const int l31  = lane & 31, g32 = lane >> 5;

  // ---- staging: thread t -> rows (t>>3, t>>3+32), 16B slot (t&7), XOR-swizzled ----
  const int r  = tid >> 3, sl = tid & 7;
  const u16* kgp = kb + (size_t)(b * 2048 + r) * 1024 + h * 64 + sl * 8;
  const u16* vgp = vt + (size_t)(bh * 64 + r) * 2048 + sl * 8;
  const int wb = r * 128 + ((sl * 16) ^ ((r & 7) << 4));   // swizzled write byte addr
  char* lK = (char*)&KV[0][0];
  char* lV = (char*)&KV[1][0];

  // ---- Q fragments: B-operand, lane holds Q[q=l31][d=dc*16+g32*8+j]; 64 rows/wave ----
  const int qrow0 = b * 2048 + qt * 256 + w * 64;
  bf16x8 qf[2][4];
#pragma unroll
  for (int q2 = 0; q2 < 2; ++q2)
#pragma unroll
    for (int dc = 0; dc < 4; ++dc)
      qf[q2][dc] = *(const bf16x8*)(qb + (size_t)(qrow0 + q2 * 32 + l31) * 1024 +
                                    h * 64 + dc * 16 + g32 * 8);

  f32x16 Oa[2][2] = {};   // [q2][db] : O^T accumulators
  float lp[2] = {0.f, 0.f};

  const int xorv = (l31 & 7) << 4;      // read-side swizzle (row&7)<<4
  const int rowb = l31 * 128;           // row byte offset within 32-row half

  // prefetch step 0 into registers
  uint4 pK0 = *(const uint4*)(kgp);
  uint4 pK1 = *(const uint4*)(kgp + (size_t)32 * 1024);
  uint4 pV0 = *(const uint4*)(vgp);
  uint4 pV1 = *(const uint4*)(vgp + (size_t)32 * 2048);

#pragma unroll 1
  for (int step = 0; step < 32; ++step) {
    __syncthreads();                 // A: all waves done READING prev tile (WAR)
    *(uint4*)(lK + wb)        = pK0;
    *(uint4*)(lK + wb + 4096) = pK1;
    *(uint4*)(lV + wb)        = pV0;
    *(uint4*)(lV + wb + 4096) = pV1;
    __syncthreads();                 // B: ds_writes visible to all waves

    if (step + 1 < 32) {             // issue next-step loads; hide under compute
      const int s1 = (step + 1) * 64;
      pK0 = *(const uint4*)(kgp + (size_t)s1 * 1024);
      pK1 = *(const uint4*)(kgp + (size_t)(s1 + 32) * 1024);
      pV0 = *(const uint4*)(vgp + s1);
      pV1 = *(const uint4*)(vgp + s1 + (size_t)32 * 2048);
    }

    const char* kt  = (const char*)&KV[0][0];
    const char* vtl = (const char*)&KV[1][0];

#pragma unroll
    for (int kb2 = 0; kb2 < 2; ++kb2) {
      // K fragments: A-operand, lane holds K[k=kb2*32+l31][d=dc*16+g32*8+j]
      bf16x8 kf[4];
#pragma unroll
      for (int dc = 0; dc < 4; ++dc)
        kf[dc] = *(const bf16x8*)(kt + kb2 * 4096 + rowb + ((dc * 32 + g32 * 16) ^ xorv));
      // V fragments: A-operand, lane holds V^T[d=db*32+l31][k=(kb2*2+ck)*16+g32*8+j]
      bf16x8 vf[2][2];
#pragma unroll
      for (int db = 0; db < 2; ++db)
#pragma unroll
        for (int ck = 0; ck < 2; ++ck)
          vf[db][ck] = *(const bf16x8*)(vtl + db * 4096 + rowb +
                                        (((kb2 * 2 + ck) * 32 + g32 * 16) ^ xorv));

#pragma unroll
      for (int q2 = 0; q2 < 2; ++q2) {
        f32x16 S = {};
#pragma unroll
        for (int dc = 0; dc < 4; ++dc)
          S = __builtin_amdgcn_mfma_f32_32x32x16_bf16(kf[dc], qf[q2][dc], S, 0, 0, 0);

        // in-register softmax (no max-sub; S pre-scaled by log2e in Q GEMM)
        float p[16];
#pragma unroll
        for (int rr = 0; rr < 16; ++rr) p[rr] = __builtin_amdgcn_exp2f(S[rr]);
        float s01 = (p[0] + p[1]) + (p[2] + p[3]);
        float s02 = (p[4] + p[5]) + (p[6] + p[7]);
        float s03 = (p[8] + p[9]) + (p[10] + p[11]);
        float s04 = (p[12] + p[13]) + (p[14] + p[15]);
        lp[q2] += (s01 + s02) + (s03 + s04);

        // ---- P^T -> bf16 B-operand words via permlane32_swap (T12) ----
        // swap(w0,w2): low lanes {own w0, partner w0}; high lanes {partner w2, own w2}
        // == v5's select form {g32?e2:w0, ..., g32?w2:e0, ...}.
        u32 w0 = pkbf(p[0], p[1]),   w1 = pkbf(p[2], p[3]);
        u32 w2 = pkbf(p[4], p[5]),   w3 = pkbf(p[6], p[7]);
        u32 w4 = pkbf(p[8], p[9]),   w5 = pkbf(p[10], p[11]);
        u32 w6 = pkbf(p[12], p[13]), w7 = pkbf(p[14], p[15]);
        u32x2 sA = __builtin_amdgcn_permlane32_swap(w0, w2, false, false);
        u32x2 sB = __builtin_amdgcn_permlane32_swap(w1, w3, false, false);
        u32x2 sC = __builtin_amdgcn_permlane32_swap(w4, w6, false, false);
        u32x2 sD = __builtin_amdgcn_permlane32_swap(w5, w7, false, false);
        u32x4v q0 = {sA[0], sB[0], sA[1], sB[1]};
        u32x4v q1 = {sC[0], sD[0], sC[1], sD[1]};
        bf16x8 pb0 = __builtin_bit_cast(bf16x8, q0);
        bf16x8 pb1 = __builtin_bit_cast(bf16x8, q1);

#pragma unroll
        for (int db = 0; db < 2; ++db) {
          Oa[q2][db] = __builtin_amdgcn_mfma_f32_32x32x16_bf16(vf[db][0], pb0, Oa[q2][db], 0, 0, 0);
          Oa[q2][db] = __builtin_amdgcn_mfma_f32_32x32x16_bf16(vf[db][1], pb1, Oa[q2][db], 0, 0, 0);
        }
      }
    }
  }

  // ---- epilogue: combine lane halves, normalize, store ----
#pragma unroll
  for (int q2 = 0; q2 < 2; ++q2) {
    float v = lp[q2];
    v += __shfl_xor(v, 32);
    float rinv = 1.0f / v;
    const size_t rb = (size_t)(qrow0 + q2 * 32 + l31) * 1024 + h * 64;
#pragma unroll
    for (int db = 0; db < 2; ++db)
#pragma unroll
      for (int pr = 0; pr < 8; ++pr) {
        int reg = 2 * pr;
        int d0  = (reg & 3) + 8 * (reg >> 2) + 4 * g32 + db * 32;
        u32 pk = pkbf(Oa[q2][db][reg] * rinv, Oa[q2][db][reg + 1] * rinv);
        *(u32*)(ob + rb + d0) = pk;
      }
  }
}

// ---------------- host ----------------
extern "C" void kernel_launch(void* const* d_in, const int* in_sizes, int n_in,
                              void* d_out, int out_size, void* d_ws, size_t ws_size,
                              hipStream_t stream) {
  const float* x  = (const float*)d_in[0];
  const float* Wk = (const float*)d_in[1];
  const float* Wq = (const float*)d_in[2];
  const float* Wv = (const float*)d_in[3];
  const float* Wp = (const float*)d_in[4];
  const float* bp = (const float*)d_in[5];
  float* out = (float*)d_out;

  const size_t MC = (size_t)8192 * 1024;
  u16* xb  = (u16*)d_ws;
  u16* qb  = xb + MC;
  u16* kb2 = qb + MC;
  u16* vtb = kb2 + MC;
  u16* wqb = vtb + MC;   // 4 weight buffers contiguous: wq, wk, wv, wp
  u16* wkb = wqb + (size_t)1024 * 1024;
  u16* wvb = wkb + (size_t)1024 * 1024;
  u16* wpb = wvb + (size_t)1024 * 1024;
  u16* ob  = xb;  // xb dead after V GEMM; reuse for attention output

  cast_bf16<<<2048, 256, 0, stream>>>(x, xb, (int)(MC / 8));
  cast4_bf16<<<dim3(256, 4), 256, 0, stream>>>(Wq, Wk, Wv, Wp, wqb, 1024 * 1024 / 8);

  const float qscale = 0.125f * 1.44269504088896340736f;  // 1/sqrt(D) * log2(e)
  dim3 gg(8, 64);  // (N/128, M/128)
  gemm_bt<0><<<gg, 256, 0, stream>>>(xb, wqb, qb,  nullptr, nullptr, qscale);  // q
  gemm_bt<0><<<gg, 256, 0, stream>>>(xb, wkb, kb2, nullptr, nullptr, 1.0f);    // k
  gemm_bt<1><<<gg, 256, 0, stream>>>(xb, wvb, vtb, nullptr, nullptr, 1.0f);    // v^T

  attn_fused<<<dim3(64, 8), 256, 0, stream>>>(qb, kb2, vtb, ob);

  gemm_bt<2><<<gg, 256, 0, stream>>>(ob, wpb, nullptr, out, bp, 1.0f);         // out proj + bias
}

// Round 13
// 183.731 us; speedup vs baseline: 6.8553x; 1.1259x over previous
//
#include <hip/hip_runtime.h>
#include <stdint.h>

typedef __bf16 bf16_t;
typedef bf16_t bf16x2 __attribute__((ext_vector_type(2)));
typedef bf16_t bf16x8 __attribute__((ext_vector_type(8)));
typedef float f32x4 __attribute__((ext_vector_type(4)));
typedef float f32x16 __attribute__((ext_vector_type(16)));
typedef unsigned short u16;
typedef u16 u16x8 __attribute__((ext_vector_type(8)));
typedef u16 u16x4 __attribute__((ext_vector_type(4)));
typedef unsigned int u32;
typedef u32 u32x2 __attribute__((ext_vector_type(2)));
typedef u32 u32x4v __attribute__((ext_vector_type(4)));

// f32 -> bf16 RTNE (inputs finite; NaN path not needed)
__device__ __forceinline__ u16 f2b(float f) {
  uint32_t u = __builtin_bit_cast(uint32_t, f);
  u += 0x7fffu + ((u >> 16) & 1u);
  return (u16)(u >> 16);
}

// pack two f32 -> one u32 of 2 bf16 via compiler casts (no inline asm)
__device__ __forceinline__ u32 pkbf(float lo, float hi) {
  bf16x2 t = {(__bf16)lo, (__bf16)hi};
  return __builtin_bit_cast(u32, t);
}

__device__ __forceinline__ void gl_lds16(const void* g, void* l) {
  __builtin_amdgcn_global_load_lds(
      (const __attribute__((address_space(1))) uint32_t*)(uintptr_t)g,
      (__attribute__((address_space(3))) uint32_t*)(uintptr_t)l, 16, 0, 0);
}

// ---------------- cast f32 -> bf16, 8 elems/thread ----------------
__global__ void cast_bf16(const float* __restrict__ src, u16* __restrict__ dst, int n8) {
  int i = blockIdx.x * blockDim.x + threadIdx.x;
  int stride = gridDim.x * blockDim.x;
  for (; i < n8; i += stride) {
    float4 a = ((const float4*)src)[2 * i];
    float4 b = ((const float4*)src)[2 * i + 1];
    u16x8 o;
    o[0] = f2b(a.x); o[1] = f2b(a.y); o[2] = f2b(a.z); o[3] = f2b(a.w);
    o[4] = f2b(b.x); o[5] = f2b(b.y); o[6] = f2b(b.z); o[7] = f2b(b.w);
    ((u16x8*)dst)[i] = o;
  }
}

// 4 weight matrices in one launch (blockIdx.y selects)
__global__ void cast4_bf16(const float* __restrict__ a, const float* __restrict__ b,
                           const float* __restrict__ c, const float* __restrict__ d,
                           u16* __restrict__ dst, int n8) {
  const float* srcs[4] = {a, b, c, d};
  const float* src = srcs[blockIdx.y];
  u16* dp = dst + (size_t)blockIdx.y * (size_t)n8 * 8;
  int i = blockIdx.x * blockDim.x + threadIdx.x;
  int stride = gridDim.x * blockDim.x;
  for (; i < n8; i += stride) {
    float4 x = ((const float4*)src)[2 * i];
    float4 y = ((const float4*)src)[2 * i + 1];
    u16x8 o;
    o[0] = f2b(x.x); o[1] = f2b(x.y); o[2] = f2b(x.z); o[3] = f2b(x.w);
    o[4] = f2b(y.x); o[5] = f2b(y.y); o[6] = f2b(y.z); o[7] = f2b(y.w);
    ((u16x8*)dp)[i] = o;
  }
}

// ---------------- merged QKV GEMM, BK=64 ----------------
// A[8192x1024] bf16 x {Wq|Wk|Wv}^T (contiguous W3). blockIdx.x>>3 selects matrix:
// 0 -> q (scaled, row-major), 1 -> k (row-major), 2 -> v^T [B*H*64][2048].
// BK=64: 16 K-iterations x 2 barriers (was 32x2 at BK=32); same ascending-k
// accumulation order -> bit-identical results.
__global__ __launch_bounds__(256, 2)
void gemm_qkv(const u16* __restrict__ A, const u16* __restrict__ W3,
              u16* __restrict__ qb, u16* __restrict__ kb2, u16* __restrict__ vtb,
              float qscale) {
  __shared__ u16 As[128 * 64];
  __shared__ u16 Bs[128 * 64];
  const int tid  = threadIdx.x;
  const int lane = tid & 63;
  const int w    = tid >> 6;
  const int wm   = w >> 1, wn = w & 1;
  const int g    = lane >> 4, c = lane & 15;
  const int which = blockIdx.x >> 3;
  const int n0    = (blockIdx.x & 7) * 128;
  const int m0    = blockIdx.y * 128;
  const u16* Wt = W3 + (size_t)which * 1024 * 1024;

  f32x4 acc[4][4] = {};

  // staging: thread t -> row t>>3 (+j*32), 16B slot t&7; LDS dest linear per wave
  const u16* gA = A  + (size_t)(m0 + (tid >> 3)) * 1024 + (tid & 7) * 8;
  const u16* gB = Wt + (size_t)(n0 + (tid >> 3)) * 1024 + (tid & 7) * 8;
  char* lA = (char*)As + w * 1024;
  char* lB = (char*)Bs + w * 1024;

#pragma unroll 1
  for (int kt = 0; kt < 1024; kt += 64) {
    __syncthreads();
#pragma unroll
    for (int j = 0; j < 4; ++j) {
      gl_lds16(gA + kt + (size_t)j * 32 * 1024, lA + j * 4096);
      gl_lds16(gB + kt + (size_t)j * 32 * 1024, lB + j * 4096);
    }
    __syncthreads();
#pragma unroll
    for (int ks = 0; ks < 2; ++ks) {
      bf16x8 af[4], bfr[4];
#pragma unroll
      for (int mi = 0; mi < 4; ++mi)
        af[mi] = *(const bf16x8*)&As[(wm * 64 + mi * 16 + c) * 64 + ks * 32 + g * 8];
#pragma unroll
      for (int ni = 0; ni < 4; ++ni)
        bfr[ni] = *(const bf16x8*)&Bs[(wn * 64 + ni * 16 + c) * 64 + ks * 32 + g * 8];
#pragma unroll
      for (int mi = 0; mi < 4; ++mi)
#pragma unroll
        for (int ni = 0; ni < 4; ++ni)
          acc[mi][ni] = __builtin_amdgcn_mfma_f32_16x16x32_bf16(af[mi], bfr[ni], acc[mi][ni], 0, 0, 0);
    }
  }

  const int rowb = m0 + wm * 64;
  const int colb = n0 + wn * 64;

  if (which <= 1) {
    u16* outb = (which == 0) ? qb : kb2;
    const float scale = (which == 0) ? qscale : 1.0f;
#pragma unroll
    for (int mi = 0; mi < 4; ++mi)
#pragma unroll
      for (int ni = 0; ni < 4; ++ni) {
        size_t base = (size_t)(rowb + mi * 16 + g * 4) * 1024 + (colb + ni * 16 + c);
#pragma unroll
        for (int r = 0; r < 4; ++r)
          outb[base + (size_t)r * 1024] = f2b(acc[mi][ni][r] * scale);
      }
  } else {
#pragma unroll
    for (int mi = 0; mi < 4; ++mi) {
      int row = rowb + mi * 16 + g * 4;
      int bb = row >> 11, tl = row & 2047;
#pragma unroll
      for (int ni = 0; ni < 4; ++ni) {
        int col = colb + ni * 16 + c;
        u16x4 pk;
#pragma unroll
        for (int r = 0; r < 4; ++r) pk[r] = f2b(acc[mi][ni][r]);
        *(u16x4*)(vtb + ((size_t)(bb * 1024 + col)) * 2048 + tl) = pk;
      }
    }
  }
}

// ---------------- output-projection GEMM, BK=64: f32 out + bias ----------------
__global__ __launch_bounds__(256, 2)
void gemm_out(const u16* __restrict__ A, const u16* __restrict__ Wt,
              float* __restrict__ outf, const float* __restrict__ bias) {
  __shared__ u16 As[128 * 64];
  __shared__ u16 Bs[128 * 64];
  const int tid  = threadIdx.x;
  const int lane = tid & 63;
  const int w    = tid >> 6;
  const int wm   = w >> 1, wn = w & 1;
  const int g    = lane >> 4, c = lane & 15;
  const int m0   = blockIdx.y * 128, n0 = blockIdx.x * 128;

  f32x4 acc[4][4] = {};

  const u16* gA = A  + (size_t)(m0 + (tid >> 3)) * 1024 + (tid & 7) * 8;
  const u16* gB = Wt + (size_t)(n0 + (tid >> 3)) * 1024 + (tid & 7) * 8;
  char* lA = (char*)As + w * 1024;
  char* lB = (char*)Bs + w * 1024;

#pragma unroll 1
  for (int kt = 0; kt < 1024; kt += 64) {
    __syncthreads();
#pragma unroll
    for (int j = 0; j < 4; ++j) {
      gl_lds16(gA + kt + (size_t)j * 32 * 1024, lA + j * 4096);
      gl_lds16(gB + kt + (size_t)j * 32 * 1024, lB + j * 4096);
    }
    __syncthreads();
#pragma unroll
    for (int ks = 0; ks < 2; ++ks) {
      bf16x8 af[4], bfr[4];
#pragma unroll
      for (int mi = 0; mi < 4; ++mi)
        af[mi] = *(const bf16x8*)&As[(wm * 64 + mi * 16 + c) * 64 + ks * 32 + g * 8];
#pragma unroll
      for (int ni = 0; ni < 4; ++ni)
        bfr[ni] = *(const bf16x8*)&Bs[(wn * 64 + ni * 16 + c) * 64 + ks * 32 + g * 8];
#pragma unroll
      for (int mi = 0; mi < 4; ++mi)
#pragma unroll
        for (int ni = 0; ni < 4; ++ni)
          acc[mi][ni] = __builtin_amdgcn_mfma_f32_16x16x32_bf16(af[mi], bfr[ni], acc[mi][ni], 0, 0, 0);
    }
  }

  const int rowb = m0 + wm * 64;
  const int colb = n0 + wn * 64;
#pragma unroll
  for (int ni = 0; ni < 4; ++ni) {
    int col = colb + ni * 16 + c;
    float bv = bias[col];
#pragma unroll
    for (int mi = 0; mi < 4; ++mi) {
      size_t base = (size_t)(rowb + mi * 16 + g * 4) * 1024 + col;
#pragma unroll
      for (int r = 0; r < 4; ++r)
        outf[base + (size_t)r * 1024] = acc[mi][ni][r] + bv;
    }
  }
}

// ---------------- fused attention v12 (unchanged champion, 81us) -------------------
// 32x32 swapped-QK, in-register softmax (exp2, log2e folded into Q GEMM scale),
// P^T via cvt_pk casts + permlane32_swap, O^T = mfma(V^T, P^T). Reg-staged
// XOR-swizzled LDS, 2-barrier step.
__global__ __launch_bounds__(256, 2)
void attn_fused(const u16* __restrict__ qb, const u16* __restrict__ kb,
                const u16* __restrict__ vt, u16* __restrict__ ob) {
  __shared__ u16 KV[2][4096];  // [0]=K (row=k, col=d), [1]=V^T (row=d, col=k); swizzled

  const int bh = blockIdx.x;            // 0..63
  const int qt = blockIdx.y;            // 0..7
  const int b  = bh >> 4, h = bh & 15;
  const int tid  = threadIdx.x;
  const int lane = tid & 63;
  const int w    = tid >> 6;
  const int l31  = lane & 31, g32 = lane >> 5;

  const int r  = tid >> 3, sl = tid & 7;
  const u16* kgp = kb + (size_t)(b * 2048 + r) * 1024 + h * 64 + sl * 8;
  const u16* vgp = vt + (size_t)(bh * 64 + r) * 2048 + sl * 8;
  const int wb = r * 128 + ((sl * 16) ^ ((r & 7) << 4));   // swizzled write byte addr
  char* lK = (char*)&KV[0][0];
  char* lV = (char*)&KV[1][0];

  const int qrow0 = b * 2048 + qt * 256 + w * 64;
  bf16x8 qf[2][4];
#pragma unroll
  for (int q2 = 0; q2 < 2; ++q2)
#pragma unroll
    for (int dc = 0; dc < 4; ++dc)
      qf[q2][dc] = *(const bf16x8*)(qb + (size_t)(qrow0 + q2 * 32 + l31) * 1024 +
                                    h * 64 + dc * 16 + g32 * 8);

  f32x16 Oa[2][2] = {};   // [q2][db] : O^T accumulators
  float lp[2] = {0.f, 0.f};

  const int xorv = (l31 & 7) << 4;      // read-side swizzle (row&7)<<4
  const int rowb = l31 * 128;           // row byte offset within 32-row half

  uint4 pK0 = *(const uint4*)(kgp);
  uint4 pK1 = *(const uint4*)(kgp + (size_t)32 * 1024);
  uint4 pV0 = *(const uint4*)(vgp);
  uint4 pV1 = *(const uint4*)(vgp + (size_t)32 * 2048);

#pragma unroll 1
  for (int step = 0; step < 32; ++step) {
    __syncthreads();                 // A: all waves done READING prev tile (WAR)
    *(uint4*)(lK + wb)        = pK0;
    *(uint4*)(lK + wb + 4096) = pK1;
    *(uint4*)(lV + wb)        = pV0;
    *(uint4*)(lV + wb + 4096) = pV1;
    __syncthreads();                 // B: ds_writes visible to all waves

    if (step + 1 < 32) {             // issue next-step loads; hide under compute
      const int s1 = (step + 1) * 64;
      pK0 = *(const uint4*)(kgp + (size_t)s1 * 1024);
      pK1 = *(const uint4*)(kgp + (size_t)(s1 + 32) * 1024);
      pV0 = *(const uint4*)(vgp + s1);
      pV1 = *(const uint4*)(vgp + s1 + (size_t)32 * 2048);
    }

    const char* kt  = (const char*)&KV[0][0];
    const char* vtl = (const char*)&KV[1][0];

#pragma unroll
    for (int kb2 = 0; kb2 < 2; ++kb2) {
      bf16x8 kf[4];
#pragma unroll
      for (int dc = 0; dc < 4; ++dc)
        kf[dc] = *(const bf16x8*)(kt + kb2 * 4096 + rowb + ((dc * 32 + g32 * 16) ^ xorv));
      bf16x8 vf[2][2];
#pragma unroll
      for (int db = 0; db < 2; ++db)
#pragma unroll
        for (int ck = 0; ck < 2; ++ck)
          vf[db][ck] = *(const bf16x8*)(vtl + db * 4096 + rowb +
                                        (((kb2 * 2 + ck) * 32 + g32 * 16) ^ xorv));

#pragma unroll
      for (int q2 = 0; q2 < 2; ++q2) {
        f32x16 S = {};
#pragma unroll
        for (int dc = 0; dc < 4; ++dc)
          S = __builtin_amdgcn_mfma_f32_32x32x16_bf16(kf[dc], qf[q2][dc], S, 0, 0, 0);

        float p[16];
#pragma unroll
        for (int rr = 0; rr < 16; ++rr) p[rr] = __builtin_amdgcn_exp2f(S[rr]);
        float s01 = (p[0] + p[1]) + (p[2] + p[3]);
        float s02 = (p[4] + p[5]) + (p[6] + p[7]);
        float s03 = (p[8] + p[9]) + (p[10] + p[11]);
        float s04 = (p[12] + p[13]) + (p[14] + p[15]);
        lp[q2] += (s01 + s02) + (s03 + s04);

        u32 w0 = pkbf(p[0], p[1]),   w1 = pkbf(p[2], p[3]);
        u32 w2 = pkbf(p[4], p[5]),   w3 = pkbf(p[6], p[7]);
        u32 w4 = pkbf(p[8], p[9]),   w5 = pkbf(p[10], p[11]);
        u32 w6 = pkbf(p[12], p[13]), w7 = pkbf(p[14], p[15]);
        u32x2 sA = __builtin_amdgcn_permlane32_swap(w0, w2, false, false);
        u32x2 sB = __builtin_amdgcn_permlane32_swap(w1, w3, false, false);
        u32x2 sC = __builtin_amdgcn_permlane32_swap(w4, w6, false, false);
        u32x2 sD = __builtin_amdgcn_permlane32_swap(w5, w7, false, false);
        u32x4v q0 = {sA[0], sB[0], sA[1], sB[1]};
        u32x4v q1 = {sC[0], sD[0], sC[1], sD[1]};
        bf16x8 pb0 = __builtin_bit_cast(bf16x8, q0);
        bf16x8 pb1 = __builtin_bit_cast(bf16x8, q1);

#pragma unroll
        for (int db = 0; db < 2; ++db) {
          Oa[q2][db] = __builtin_amdgcn_mfma_f32_32x32x16_bf16(vf[db][0], pb0, Oa[q2][db], 0, 0, 0);
          Oa[q2][db] = __builtin_amdgcn_mfma_f32_32x32x16_bf16(vf[db][1], pb1, Oa[q2][db], 0, 0, 0);
        }
      }
    }
  }

#pragma unroll
  for (int q2 = 0; q2 < 2; ++q2) {
    float v = lp[q2];
    v += __shfl_xor(v, 32);
    float rinv = 1.0f / v;
    const size_t rb = (size_t)(qrow0 + q2 * 32 + l31) * 1024 + h * 64;
#pragma unroll
    for (int db = 0; db < 2; ++db)
#pragma unroll
      for (int pr = 0; pr < 8; ++pr) {
        int reg = 2 * pr;
        int d0  = (reg & 3) + 8 * (reg >> 2) + 4 * g32 + db * 32;
        u32 pk = pkbf(Oa[q2][db][reg] * rinv, Oa[q2][db][reg + 1] * rinv);
        *(u32*)(ob + rb + d0) = pk;
      }
  }
}

// ---------------- host ----------------
extern "C" void kernel_launch(void* const* d_in, const int* in_sizes, int n_in,
                              void* d_out, int out_size, void* d_ws, size_t ws_size,
                              hipStream_t stream) {
  const float* x  = (const float*)d_in[0];
  const float* Wk = (const float*)d_in[1];
  const float* Wq = (const float*)d_in[2];
  const float* Wv = (const float*)d_in[3];
  const float* Wp = (const float*)d_in[4];
  const float* bp = (const float*)d_in[5];
  float* out = (float*)d_out;

  const size_t MC = (size_t)8192 * 1024;
  u16* xb  = (u16*)d_ws;
  u16* qb  = xb + MC;
  u16* kb2 = qb + MC;
  u16* vtb = kb2 + MC;
  u16* wqb = vtb + MC;   // 4 weight buffers contiguous: wq, wk, wv, wp
  u16* wpb = wqb + (size_t)3 * 1024 * 1024;
  u16* ob  = xb;  // xb dead after QKV GEMM; reuse for attention output

  cast_bf16<<<2048, 256, 0, stream>>>(x, xb, (int)(MC / 8));
  cast4_bf16<<<dim3(256, 4), 256, 0, stream>>>(Wq, Wk, Wv, Wp, wqb, 1024 * 1024 / 8);

  const float qscale = 0.125f * 1.44269504088896340736f;  // 1/sqrt(D) * log2(e)
  gemm_qkv<<<dim3(24, 64), 256, 0, stream>>>(xb, wqb, qb, kb2, vtb, qscale);

  attn_fused<<<dim3(64, 8), 256, 0, stream>>>(qb, kb2, vtb, ob);

  gemm_out<<<dim3(8, 64), 256, 0, stream>>>(ob, wpb, out, bp);
}